// Round 1
// baseline (54.134 us; speedup 1.0000x reference)
//
#include <hip/hip_runtime.h>

#define MCW_EPS 1e-32f

// ---------------------------------------------------------------------------
// Main pass: stream output+labels once.
//   Per column c: sum_s_pos[c], sum_s_neg[c], n_pos[c]   (float atomics)
//   Global:       sum(labels*log(s+eps)), sum((1-l)*log(1-s+eps))  (double atomics)
// Layout: row-major [B, 256]. Block = 256 threads; thread t loads a float4 at
// row (rg*4 + t/64), cols 4*(t&63)..+3 -> 16B/lane fully coalesced (1KB/row
// per 64-lane group).
// ---------------------------------------------------------------------------
__global__ __launch_bounds__(256) void mcwauc_main(
    const float* __restrict__ x_, const float* __restrict__ l_,
    int rowGroups,
    float* __restrict__ g_sp, float* __restrict__ g_sn, float* __restrict__ g_np,
    double* __restrict__ g_logs)
{
    const int t       = threadIdx.x;
    const int lane_rg = t >> 6;          // which of 4 rows in the row-group
    const int c0      = (t & 63) << 2;   // base column (4 consecutive cols)

    float sp[4] = {0.f, 0.f, 0.f, 0.f};
    float sn[4] = {0.f, 0.f, 0.f, 0.f};
    float np[4] = {0.f, 0.f, 0.f, 0.f};
    float lp = 0.f, ln = 0.f;

    for (int rg = blockIdx.x; rg < rowGroups; rg += gridDim.x) {
        const size_t row = (size_t)(rg << 2) + lane_rg;
        const size_t idx = row * 256 + c0;
        const float4 x = *reinterpret_cast<const float4*>(x_ + idx);
        const float4 l = *reinterpret_cast<const float4*>(l_ + idx);
        #pragma unroll
        for (int k = 0; k < 4; ++k) {
            const float xv = (&x.x)[k];
            const float lv = (&l.x)[k];
            const float e   = __expf(-xv);
            const float s   = 1.f / (1.f + e);   // sigmoid(x)
            const float s1  = e * s;             // 1 - sigmoid(x), no cancellation
            if (lv != 0.f) {
                sp[k] += s;
                np[k] += 1.f;
                lp    += __logf(s + MCW_EPS);
            } else {
                sn[k] += s;
                ln    += __logf(s1 + MCW_EPS);
            }
        }
    }

    // ---- block reduce per-column partials (4 row-lanes -> 1 per column) ----
    __shared__ float rp[4][256];
    __shared__ float rn[4][256];
    __shared__ float rc[4][256];
    #pragma unroll
    for (int k = 0; k < 4; ++k) {
        rp[lane_rg][c0 + k] = sp[k];
        rn[lane_rg][c0 + k] = sn[k];
        rc[lane_rg][c0 + k] = np[k];
    }

    // ---- wave-reduce the global log sums while LDS settles ----
    #pragma unroll
    for (int o = 32; o > 0; o >>= 1) {
        lp += __shfl_down(lp, o);
        ln += __shfl_down(ln, o);
    }
    __shared__ float wl[2][4];
    if ((t & 63) == 0) { wl[0][t >> 6] = lp; wl[1][t >> 6] = ln; }

    __syncthreads();

    {
        const int c = t;  // 256 threads == 256 columns
        const float a = rp[0][c] + rp[1][c] + rp[2][c] + rp[3][c];
        const float b = rn[0][c] + rn[1][c] + rn[2][c] + rn[3][c];
        const float d = rc[0][c] + rc[1][c] + rc[2][c] + rc[3][c];
        atomicAdd(&g_sp[c], a);
        atomicAdd(&g_sn[c], b);
        atomicAdd(&g_np[c], d);
    }
    if (t == 0) {
        atomicAdd(&g_logs[0], (double)(wl[0][0] + wl[0][1] + wl[0][2] + wl[0][3]));
        atomicAdd(&g_logs[1], (double)(wl[1][0] + wl[1][1] + wl[1][2] + wl[1][3]));
    }
}

// ---------------------------------------------------------------------------
// Finalize: 1 block x 256 threads (one per column).
// ---------------------------------------------------------------------------
__global__ __launch_bounds__(256) void mcwauc_fin(
    const float* __restrict__ g_sp, const float* __restrict__ g_sn,
    const float* __restrict__ g_np, const double* __restrict__ g_logs,
    float* __restrict__ out, int B)
{
    const int c = threadIdx.x;
    const float np = g_np[c];
    const float nn = (float)B - np;
    const float mp = g_sp[c] / fmaxf(np, 1.f);
    const float mn = g_sn[c] / fmaxf(nn, 1.f);

    float pen;
    if (np > 0.f && nn > 0.f)      pen = 1.f - mp + mn;
    else if (np == 0.f)            pen = 1.f + mn;
    else                           pen = 1.f - mp;

    // reduce pen-sum and num_P across the 256 threads
    float psum = pen, csum = np;
    #pragma unroll
    for (int o = 32; o > 0; o >>= 1) {
        psum += __shfl_down(psum, o);
        csum += __shfl_down(csum, o);
    }
    __shared__ float sps[4], scs[4];
    if ((c & 63) == 0) { sps[c >> 6] = psum; scs[c >> 6] = csum; }
    __syncthreads();

    if (c == 255) out[1] = 0.1f * pen;   // penalty term of the LAST category
    if (c == 0) {
        const double pensum = (double)sps[0] + sps[1] + sps[2] + sps[3];
        const double numP   = (double)scs[0] + scs[1] + scs[2] + scs[3];
        const double total  = (double)B * 256.0;
        const double aP = numP / total;
        const double aN = 1.0 - aP;
        const double cel = -aN * (g_logs[0] / total) - aP * (g_logs[1] / total);
        const double cls = cel + 0.1 * (pensum / 256.0);
        out[0] = (float)cls;
    }
}

extern "C" void kernel_launch(void* const* d_in, const int* in_sizes, int n_in,
                              void* d_out, int out_size, void* d_ws, size_t ws_size,
                              hipStream_t stream) {
    const float* x = (const float*)d_in[0];
    const float* l = (const float*)d_in[1];
    const int n = in_sizes[0];
    const int B = n / 256;

    float*  g_sp   = (float*)d_ws;
    float*  g_sn   = g_sp + 256;
    float*  g_np   = g_sn + 256;
    double* g_logs = (double*)((char*)d_ws + 3 * 256 * sizeof(float)); // 3072 % 8 == 0

    // zero the accumulators every call (harness poisons ws once; we accumulate)
    hipMemsetAsync(d_ws, 0, 3 * 256 * sizeof(float) + 2 * sizeof(double), stream);

    const int rowGroups = B / 4;           // B = 65536 -> 16384
    int grid = 1024;
    if (grid > rowGroups) grid = rowGroups;

    mcwauc_main<<<grid, 256, 0, stream>>>(x, l, rowGroups, g_sp, g_sn, g_np, g_logs);
    mcwauc_fin<<<1, 256, 0, stream>>>(g_sp, g_sn, g_np, g_logs, (float*)d_out, B);
}